// Round 1
// baseline (2085.308 us; speedup 1.0000x reference)
//
#include <hip/hip_runtime.h>
#include <math.h>

// Problem: MHSA forward. x[16,1024,512]f32, w_qkv[512,1536], w_out[512,512], b_out[512].
// out[16,1024,512] = softmax((xWq)(xWk)^T * 512^-0.5) (xWv) @ w_out + b_out, 8 heads, dh=64.
// Round 1: correct f32 baseline. ws: qkv[16384,1536]f32 (96MiB) + attn_out[16384,512]f32 (32MiB).

#define SCALE_ 0.04419417382415922f   // 512^-0.5
#define NB_ 16
#define NN_ 1024
#define NDIM_ 512

// ---------------- C[M,N] = A[M,K] @ B[K,N] (+bias), 64x64x16 tiles ----------------
__global__ __launch_bounds__(256) void gemm_f32(const float* __restrict__ A,
                                                const float* __restrict__ Bm,
                                                const float* __restrict__ bias,
                                                float* __restrict__ C,
                                                int M, int N, int K) {
    __shared__ float As[16][65];   // [k][m], padded: inner reads broadcast per ty
    __shared__ float Bs[16][64];   // [k][n]
    const int tid = threadIdx.x;
    const int tx = tid & 15;       // N dir, 4 cols each
    const int ty = tid >> 4;       // M dir, 4 rows each
    const int rowBase = blockIdx.y * 64;
    const int colBase = blockIdx.x * 64;

    const int a_k = tid & 15;      // 0..15
    const int a_r = tid >> 4;      // 0..15 (+0,16,32,48)
    const int b_c = tid & 63;      // 0..63
    const int b_k = tid >> 6;      // 0..3 (+0,4,8,12)

    float acc[4][4] = {};

    for (int k0 = 0; k0 < K; k0 += 16) {
#pragma unroll
        for (int r = 0; r < 64; r += 16)
            As[a_k][a_r + r] = A[(size_t)(rowBase + a_r + r) * K + k0 + a_k];
#pragma unroll
        for (int kk = 0; kk < 16; kk += 4)
            Bs[b_k + kk][b_c] = Bm[(size_t)(k0 + b_k + kk) * N + colBase + b_c];
        __syncthreads();
#pragma unroll
        for (int kk = 0; kk < 16; ++kk) {
            float a_f[4], b_f[4];
#pragma unroll
            for (int i = 0; i < 4; ++i) a_f[i] = As[kk][ty * 4 + i];
#pragma unroll
            for (int j = 0; j < 4; ++j) b_f[j] = Bs[kk][tx * 4 + j];
#pragma unroll
            for (int i = 0; i < 4; ++i)
#pragma unroll
                for (int j = 0; j < 4; ++j)
                    acc[i][j] = fmaf(a_f[i], b_f[j], acc[i][j]);
        }
        __syncthreads();
    }
#pragma unroll
    for (int i = 0; i < 4; ++i) {
        const int row = rowBase + ty * 4 + i;
#pragma unroll
        for (int j = 0; j < 4; ++j) {
            const int col = colBase + tx * 4 + j;
            float v = acc[i][j];
            if (bias) v += bias[col];
            C[(size_t)row * N + col] = v;
        }
    }
}

// ---------------- flash attention, one WG = (b,h) x 64-row Q tile ----------------
// qkv rows are [q(512) | k(512) | v(512)]; head h uses cols h*64..h*64+63 of each.
__global__ __launch_bounds__(256) void attn_flash(const float* __restrict__ qkv,
                                                  float* __restrict__ aout) {
    const int qt = blockIdx.x;            // 0..15
    const int bh = blockIdx.y;            // 0..127
    const int b = bh >> 3, h = bh & 7;
    const int tid = threadIdx.x;
    const int row = tid >> 2;             // 0..63  q-row in tile
    const int quad = tid & 3;             // 0..3   owns 16 cols (of S and of O)

    __shared__ float Qs[64][65];
    __shared__ float KVs[64][65];         // K tile, then reused for V tile
    __shared__ float Ps[64][65];

    const size_t base = (size_t)b * NN_ * 1536;
    const int qrow0 = qt * 64;
    const int lc = tid & 63;              // loader: col
    const int lr0 = tid >> 6;             // loader: row start (0..3)

    for (int r = lr0; r < 64; r += 4)
        Qs[r][lc] = qkv[base + (size_t)(qrow0 + r) * 1536 + h * 64 + lc];

    float o[16];
#pragma unroll
    for (int i = 0; i < 16; ++i) o[i] = 0.f;
    float m = -INFINITY, l = 0.f;

    __syncthreads();

    for (int kt = 0; kt < 16; ++kt) {
        // K tile
        for (int r = lr0; r < 64; r += 4)
            KVs[r][lc] = qkv[base + (size_t)(kt * 64 + r) * 1536 + 512 + h * 64 + lc];
        __syncthreads();

        // S[row][quad*16+jj] = Q[row]·K[j] * scale   (d-outer: 17 LDS reads / 16 FMA)
        float s[16];
#pragma unroll
        for (int jj = 0; jj < 16; ++jj) s[jj] = 0.f;
        for (int d = 0; d < 64; ++d) {
            const float qd = Qs[row][d];
#pragma unroll
            for (int jj = 0; jj < 16; ++jj)
                s[jj] = fmaf(qd, KVs[quad * 16 + jj][d], s[jj]);
        }
        float tmax = s[0] * SCALE_;
#pragma unroll
        for (int jj = 0; jj < 16; ++jj) { s[jj] *= SCALE_; tmax = fmaxf(tmax, s[jj]); }
        tmax = fmaxf(tmax, __shfl_xor(tmax, 1, 4));
        tmax = fmaxf(tmax, __shfl_xor(tmax, 2, 4));
        const float mnew = fmaxf(m, tmax);
        const float corr = __expf(m - mnew);      // exp(-inf)=0 on first tile
        float psum = 0.f;
#pragma unroll
        for (int jj = 0; jj < 16; ++jj) {
            s[jj] = __expf(s[jj] - mnew);
            psum += s[jj];
        }
        psum += __shfl_xor(psum, 1, 4);
        psum += __shfl_xor(psum, 2, 4);
        l = l * corr + psum;
        m = mnew;
#pragma unroll
        for (int i = 0; i < 16; ++i) o[i] *= corr;
#pragma unroll
        for (int jj = 0; jj < 16; ++jj) Ps[row][quad * 16 + jj] = s[jj];
        __syncthreads();                  // P written; everyone done reading K

        // V tile (overwrites K buffer)
        for (int r = lr0; r < 64; r += 4)
            KVs[r][lc] = qkv[base + (size_t)(kt * 64 + r) * 1536 + 1024 + h * 64 + lc];
        __syncthreads();

        // O[row][quad*16+dd] += sum_j P[row][j] * V[j][...]
        for (int j = 0; j < 64; ++j) {
            const float p = Ps[row][j];
#pragma unroll
            for (int dd = 0; dd < 16; ++dd)
                o[dd] = fmaf(p, KVs[j][quad * 16 + dd], o[dd]);
        }
        __syncthreads();                  // before next iter overwrites KVs/Ps
    }

    const float inv = 1.f / l;
    const size_t orow = (size_t)(b * NN_ + qrow0 + row) * NDIM_ + h * 64 + quad * 16;
#pragma unroll
    for (int dd = 0; dd < 16; ++dd)
        aout[orow + dd] = o[dd] * inv;
}

extern "C" void kernel_launch(void* const* d_in, const int* in_sizes, int n_in,
                              void* d_out, int out_size, void* d_ws, size_t ws_size,
                              hipStream_t stream) {
    const float* x     = (const float*)d_in[0];
    const float* w_qkv = (const float*)d_in[1];
    const float* w_out = (const float*)d_in[2];
    const float* b_out = (const float*)d_in[3];
    float* out = (float*)d_out;

    float* qkv  = (float*)d_ws;                       // [16384,1536]
    float* aout = qkv + (size_t)16384 * 1536;         // [16384,512]

    const dim3 blk(256);
    // qkv = x @ w_qkv : M=16384 N=1536 K=512
    gemm_f32<<<dim3(1536 / 64, 16384 / 64), blk, 0, stream>>>(x, w_qkv, nullptr, qkv,
                                                              16384, 1536, 512);
    // attention per (b,h,qtile)
    attn_flash<<<dim3(16, 128), blk, 0, stream>>>(qkv, aout);
    // out = aout @ w_out + b_out : M=16384 N=512 K=512
    gemm_f32<<<dim3(512 / 64, 16384 / 64), blk, 0, stream>>>(aout, w_out, b_out, out,
                                                             16384, 512, 512);
}

// Round 2
// 1033.693 us; speedup vs baseline: 2.0173x; 2.0173x over previous
//
#include <hip/hip_runtime.h>
#include <math.h>

// MHSA forward. x[16,1024,512]f32, w_qkv[512,1536], w_out[512,512], b_out[512].
// Round 2: register-blocked f32 attention (4x4 micro-tiles, float4 LDS), float4 GEMM frags.
// ws: qkv[16384,1536]f32 (96MiB) + attn_out[16384,512]f32 (32MiB).

#define SCALE_ 0.04419417382415922f   // 512^-0.5
#define NN_ 1024
#define NDIM_ 512

// ---------------- C[M,N] = A[M,K] @ B[K,N] (+bias), 64x64x16 tiles, 4x4 regs ----------------
__global__ __launch_bounds__(256) void gemm_f32(const float* __restrict__ A,
                                                const float* __restrict__ Bm,
                                                const float* __restrict__ bias,
                                                float* __restrict__ C,
                                                int M, int N, int K) {
    __shared__ float As[16][68];   // [k][m]
    __shared__ float Bs[16][68];   // [k][n]
    const int tid = threadIdx.x;
    const int tx = tid & 15;       // N dir, 4 cols
    const int ty = tid >> 4;       // M dir, 4 rows
    const int rowBase = blockIdx.y * 64;
    const int colBase = blockIdx.x * 64;

    const int a_row = tid >> 2, a_k4 = tid & 3;    // A: one float4 (4 k) per thread
    const int b_k = tid >> 4, b_c4 = tid & 15;     // B: one float4 (4 n) per thread

    float acc[4][4] = {};

    for (int k0 = 0; k0 < K; k0 += 16) {
        const float4 av = *(const float4*)&A[(size_t)(rowBase + a_row) * K + k0 + a_k4 * 4];
        As[a_k4 * 4 + 0][a_row] = av.x;
        As[a_k4 * 4 + 1][a_row] = av.y;
        As[a_k4 * 4 + 2][a_row] = av.z;
        As[a_k4 * 4 + 3][a_row] = av.w;
        *(float4*)&Bs[b_k][b_c4 * 4] =
            *(const float4*)&Bm[(size_t)(k0 + b_k) * N + colBase + b_c4 * 4];
        __syncthreads();
#pragma unroll
        for (int kk = 0; kk < 16; ++kk) {
            const float4 a_f = *(const float4*)&As[kk][ty * 4];
            const float4 b_f = *(const float4*)&Bs[kk][tx * 4];
            const float af[4] = {a_f.x, a_f.y, a_f.z, a_f.w};
            const float bf[4] = {b_f.x, b_f.y, b_f.z, b_f.w};
#pragma unroll
            for (int i = 0; i < 4; ++i)
#pragma unroll
                for (int j = 0; j < 4; ++j)
                    acc[i][j] = fmaf(af[i], bf[j], acc[i][j]);
        }
        __syncthreads();
    }
#pragma unroll
    for (int i = 0; i < 4; ++i) {
        const int row = rowBase + ty * 4 + i;
        float4 v = make_float4(acc[i][0], acc[i][1], acc[i][2], acc[i][3]);
        if (bias) {
            const float4 bv = *(const float4*)&bias[colBase + tx * 4];
            v.x += bv.x; v.y += bv.y; v.z += bv.z; v.w += bv.w;
        }
        *(float4*)&C[(size_t)row * N + colBase + tx * 4] = v;
    }
}

// ---------------- flash attention, one WG = (b,h) x 64-row Q tile ----------------
// qkv rows are [q(512) | k(512) | v(512)]; head h uses cols h*64..h*64+63.
// Thread (tm,tn): S block rows 4tm..4tm+3, cols {tn+16j}; O block rows 4tm.., cols 4tn..4tn+3.
__global__ __launch_bounds__(256) void attn_flash(const float* __restrict__ qkv,
                                                  float* __restrict__ aout) {
    const int qt = blockIdx.x;            // 0..15
    const int bh = blockIdx.y;            // 0..127
    const int b = bh >> 3, h = bh & 7;
    const int tid = threadIdx.x;
    const int tm = tid >> 4;              // 0..15
    const int tn = tid & 15;              // 0..15

    __shared__ float Qs[64][68];
    __shared__ float KVs[64][68];         // K tile, then V tile
    __shared__ float Ps[64][68];

    const size_t base = (size_t)b * NN_ * 1536;
    const int qrow0 = qt * 64;
    const int lc4 = tid & 15;             // loader float4-col 0..15
    const int lr = tid >> 4;              // loader row start 0..15

    for (int r = lr; r < 64; r += 16)
        *(float4*)&Qs[r][lc4 * 4] =
            *(const float4*)&qkv[base + (size_t)(qrow0 + r) * 1536 + h * 64 + lc4 * 4];

    float o[4][4] = {};
    float m[4], l[4];
#pragma unroll
    for (int i = 0; i < 4; ++i) { m[i] = -INFINITY; l[i] = 0.f; }

    __syncthreads();

    for (int kt = 0; kt < 16; ++kt) {
        // ---- K tile ----
        for (int r = lr; r < 64; r += 16)
            *(float4*)&KVs[r][lc4 * 4] =
                *(const float4*)&qkv[base + (size_t)(kt * 64 + r) * 1536 + 512 + h * 64 + lc4 * 4];
        __syncthreads();

        // ---- S = Q K^T * scale ----
        float s[4][4] = {};
#pragma unroll 4
        for (int d0 = 0; d0 < 64; d0 += 4) {
            float4 qv[4], kv[4];
#pragma unroll
            for (int i = 0; i < 4; ++i) qv[i] = *(const float4*)&Qs[tm * 4 + i][d0];
#pragma unroll
            for (int j = 0; j < 4; ++j) kv[j] = *(const float4*)&KVs[tn + 16 * j][d0];
#pragma unroll
            for (int i = 0; i < 4; ++i)
#pragma unroll
                for (int j = 0; j < 4; ++j) {
                    s[i][j] = fmaf(qv[i].x, kv[j].x, s[i][j]);
                    s[i][j] = fmaf(qv[i].y, kv[j].y, s[i][j]);
                    s[i][j] = fmaf(qv[i].z, kv[j].z, s[i][j]);
                    s[i][j] = fmaf(qv[i].w, kv[j].w, s[i][j]);
                }
        }

        // ---- online softmax (row groups = 16 contiguous lanes, shfl width 16) ----
#pragma unroll
        for (int i = 0; i < 4; ++i) {
            float tmax = -INFINITY;
#pragma unroll
            for (int j = 0; j < 4; ++j) { s[i][j] *= SCALE_; tmax = fmaxf(tmax, s[i][j]); }
            tmax = fmaxf(tmax, __shfl_xor(tmax, 1, 16));
            tmax = fmaxf(tmax, __shfl_xor(tmax, 2, 16));
            tmax = fmaxf(tmax, __shfl_xor(tmax, 4, 16));
            tmax = fmaxf(tmax, __shfl_xor(tmax, 8, 16));
            const float mnew = fmaxf(m[i], tmax);
            const float corr = __expf(m[i] - mnew);   // exp(-inf)=0 first tile
            float psum = 0.f;
#pragma unroll
            for (int j = 0; j < 4; ++j) {
                s[i][j] = __expf(s[i][j] - mnew);
                psum += s[i][j];
            }
            psum += __shfl_xor(psum, 1, 16);
            psum += __shfl_xor(psum, 2, 16);
            psum += __shfl_xor(psum, 4, 16);
            psum += __shfl_xor(psum, 8, 16);
            l[i] = l[i] * corr + psum;
            m[i] = mnew;
#pragma unroll
            for (int dd = 0; dd < 4; ++dd) o[i][dd] *= corr;
        }

        // ---- write P ----
#pragma unroll
        for (int i = 0; i < 4; ++i)
#pragma unroll
            for (int j = 0; j < 4; ++j)
                Ps[tm * 4 + i][tn + 16 * j] = s[i][j];
        __syncthreads();                  // P visible; all done reading K

        // ---- V tile (overwrites K buffer) ----
        for (int r = lr; r < 64; r += 16)
            *(float4*)&KVs[r][lc4 * 4] =
                *(const float4*)&qkv[base + (size_t)(kt * 64 + r) * 1536 + 1024 + h * 64 + lc4 * 4];
        __syncthreads();

        // ---- O += P V ----
#pragma unroll 4
        for (int j0 = 0; j0 < 64; j0 += 4) {
            float4 pv[4], vv[4];
#pragma unroll
            for (int i = 0; i < 4; ++i) pv[i] = *(const float4*)&Ps[tm * 4 + i][j0];
#pragma unroll
            for (int jj = 0; jj < 4; ++jj) vv[jj] = *(const float4*)&KVs[j0 + jj][tn * 4];
#pragma unroll
            for (int i = 0; i < 4; ++i) {
                const float pf[4] = {pv[i].x, pv[i].y, pv[i].z, pv[i].w};
                const float* vf0 = (const float*)&vv[0];
                const float* vf1 = (const float*)&vv[1];
                const float* vf2 = (const float*)&vv[2];
                const float* vf3 = (const float*)&vv[3];
#pragma unroll
                for (int dd = 0; dd < 4; ++dd) {
                    float acc = o[i][dd];
                    acc = fmaf(pf[0], vf0[dd], acc);
                    acc = fmaf(pf[1], vf1[dd], acc);
                    acc = fmaf(pf[2], vf2[dd], acc);
                    acc = fmaf(pf[3], vf3[dd], acc);
                    o[i][dd] = acc;
                }
            }
        }
        __syncthreads();                  // before next iter overwrites KVs/Ps
    }

#pragma unroll
    for (int i = 0; i < 4; ++i) {
        const float inv = 1.f / l[i];
        const size_t orow = (size_t)(b * NN_ + qrow0 + tm * 4 + i) * NDIM_ + h * 64 + tn * 4;
        const float4 r = make_float4(o[i][0] * inv, o[i][1] * inv, o[i][2] * inv, o[i][3] * inv);
        *(float4*)&aout[orow] = r;
    }
}

extern "C" void kernel_launch(void* const* d_in, const int* in_sizes, int n_in,
                              void* d_out, int out_size, void* d_ws, size_t ws_size,
                              hipStream_t stream) {
    const float* x     = (const float*)d_in[0];
    const float* w_qkv = (const float*)d_in[1];
    const float* w_out = (const float*)d_in[2];
    const float* b_out = (const float*)d_in[3];
    float* out = (float*)d_out;

    float* qkv  = (float*)d_ws;                       // [16384,1536]
    float* aout = qkv + (size_t)16384 * 1536;         // [16384,512]

    const dim3 blk(256);
    gemm_f32<<<dim3(1536 / 64, 16384 / 64), blk, 0, stream>>>(x, w_qkv, nullptr, qkv,
                                                              16384, 1536, 512);
    attn_flash<<<dim3(16, 128), blk, 0, stream>>>(qkv, aout);
    gemm_f32<<<dim3(512 / 64, 16384 / 64), blk, 0, stream>>>(aout, w_out, b_out, out,
                                                             16384, 512, 512);
}

// Round 3
// 617.462 us; speedup vs baseline: 3.3772x; 1.6741x over previous
//
#include <hip/hip_runtime.h>
#include <math.h>

// MHSA forward. x[16,1024,512]f32, w_qkv[512,1536], w_out[512,512], b_out[512].
// Round 3: bf16 MFMA GEMMs (m97 structure), attention f32 unchanged (bf16 aout epilogue).
// ws: qkv_f32[16384,1536] | xb/aoutb bf16[16384,512] (aliased) | wqkvT bf16[1536,512] | woutT bf16[512,512]

#define SCALE_ 0.04419417382415922f   // 512^-0.5
#define NN_ 1024
#define NDIM_ 512

typedef float f32x4 __attribute__((ext_vector_type(4)));
typedef __bf16 bf16x8 __attribute__((ext_vector_type(8)));

static __device__ __forceinline__ ushort bf_bits(float f) {
    unsigned u = __builtin_bit_cast(unsigned, f);
    u += 0x7fffu + ((u >> 16) & 1u);          // RNE
    return (ushort)(u >> 16);
}

#define GLDS16(gsrc, ldst)                                                              \
    __builtin_amdgcn_global_load_lds((const __attribute__((address_space(1))) void*)(gsrc), \
                                     (__attribute__((address_space(3))) void*)(ldst), 16, 0, 0)

// ---------------- cast f32 -> bf16, 4 elems/thread ----------------
__global__ __launch_bounds__(256) void cast_bf16(const float* __restrict__ in,
                                                 ushort* __restrict__ out, int n4) {
    const int i = blockIdx.x * 256 + threadIdx.x;
    if (i >= n4) return;
    const float4 v = ((const float4*)in)[i];
    ushort4 o;
    o.x = bf_bits(v.x); o.y = bf_bits(v.y); o.z = bf_bits(v.z); o.w = bf_bits(v.w);
    ((ushort4*)out)[i] = o;
}

// ---------------- transpose-cast: in[K,N] f32 -> out[N,K] bf16 ----------------
__global__ __launch_bounds__(256) void transpose_cast(const float* __restrict__ in,
                                                      ushort* __restrict__ out,
                                                      int K, int N) {
    __shared__ float t[32][33];
    const int n0 = blockIdx.x * 32, k0 = blockIdx.y * 32;
    const int tx = threadIdx.x & 31, ty = threadIdx.x >> 5;
    for (int i = ty; i < 32; i += 8)
        t[i][tx] = in[(size_t)(k0 + i) * N + n0 + tx];
    __syncthreads();
    for (int i = ty; i < 32; i += 8)
        out[(size_t)(n0 + i) * K + k0 + tx] = bf_bits(t[tx][i]);
}

// ---------------- C[M,N] = A[M,K] @ BT[N,K]^T (+bias), bf16 MFMA ----------------
// 128x128 tile, BK=32, 4 waves (2x2), each wave 64x64 = 4x4 fragments of 16x16x32.
__global__ __launch_bounds__(256) void gemm_bf16(const ushort* __restrict__ A,
                                                 const ushort* __restrict__ BT,
                                                 const float* __restrict__ bias,
                                                 float* __restrict__ C,
                                                 int M, int N, int K) {
    __shared__ __align__(16) char lds[16384];   // A-tile [0,8192): [128 m][32 k] bf16; B-tile +8192: [128 n][32 k]
    const int tid = threadIdx.x;
    const int lane = tid & 63;
    const int w = tid >> 6;
    const int wr = w >> 1, wc = w & 1;
    const int fr = lane & 15;       // fragment row/col within 16
    const int fg = lane >> 4;       // k-group 0..3
    const int rowBase = blockIdx.y * 128;
    const int colBase = blockIdx.x * 128;

    f32x4 acc[4][4] = {};

    for (int k0 = 0; k0 < K; k0 += 32) {
        // stage A and B tiles: per wave, 2 rounds each, 16B/lane
#pragma unroll
        for (int r = 0; r < 2; ++r) {
            const unsigned boff = r * 4096u + w * 1024u + lane * 16u;
            const unsigned row = boff >> 6;           // 0..127
            const unsigned ke = (boff & 63u) >> 1;    // bf16 idx within row
            GLDS16(A + (size_t)(rowBase + row) * K + k0 + ke, lds + r * 4096 + w * 1024);
            GLDS16(BT + (size_t)(colBase + row) * K + k0 + ke, lds + 8192 + r * 4096 + w * 1024);
        }
        __syncthreads();

        bf16x8 a_frag[4], b_frag[4];
#pragma unroll
        for (int mi = 0; mi < 4; ++mi)
            a_frag[mi] = *(const bf16x8*)(lds + ((wr * 64 + mi * 16 + fr) * 64 + fg * 16));
#pragma unroll
        for (int ni = 0; ni < 4; ++ni)
            b_frag[ni] = *(const bf16x8*)(lds + 8192 + ((wc * 64 + ni * 16 + fr) * 64 + fg * 16));
#pragma unroll
        for (int mi = 0; mi < 4; ++mi)
#pragma unroll
            for (int ni = 0; ni < 4; ++ni)
                acc[mi][ni] = __builtin_amdgcn_mfma_f32_16x16x32_bf16(a_frag[mi], b_frag[ni],
                                                                      acc[mi][ni], 0, 0, 0);
        __syncthreads();
    }

    // C/D layout: col = lane&15, row = (lane>>4)*4 + reg
#pragma unroll
    for (int ni = 0; ni < 4; ++ni) {
        const int col = colBase + wc * 64 + ni * 16 + fr;
        const float bv = bias ? bias[col] : 0.f;
#pragma unroll
        for (int mi = 0; mi < 4; ++mi) {
#pragma unroll
            for (int q = 0; q < 4; ++q) {
                const int row = rowBase + wr * 64 + mi * 16 + fg * 4 + q;
                C[(size_t)row * N + col] = acc[mi][ni][q] + bv;
            }
        }
    }
}

// ---------------- flash attention (f32), one WG = (b,h) x 64-row Q tile ----------------
// qkv rows [q(512)|k(512)|v(512)] f32; head h uses cols h*64..h*64+63. Output bf16.
__global__ __launch_bounds__(256) void attn_flash(const float* __restrict__ qkv,
                                                  ushort* __restrict__ aoutb) {
    const int qt = blockIdx.x;
    const int bh = blockIdx.y;
    const int b = bh >> 3, h = bh & 7;
    const int tid = threadIdx.x;
    const int tm = tid >> 4;
    const int tn = tid & 15;

    __shared__ float Qs[64][68];
    __shared__ float KVs[64][68];
    __shared__ float Ps[64][68];

    const size_t base = (size_t)b * NN_ * 1536;
    const int qrow0 = qt * 64;
    const int lc4 = tid & 15;
    const int lr = tid >> 4;

    for (int r = lr; r < 64; r += 16)
        *(float4*)&Qs[r][lc4 * 4] =
            *(const float4*)&qkv[base + (size_t)(qrow0 + r) * 1536 + h * 64 + lc4 * 4];

    float o[4][4] = {};
    float m[4], l[4];
#pragma unroll
    for (int i = 0; i < 4; ++i) { m[i] = -INFINITY; l[i] = 0.f; }

    __syncthreads();

    for (int kt = 0; kt < 16; ++kt) {
        for (int r = lr; r < 64; r += 16)
            *(float4*)&KVs[r][lc4 * 4] =
                *(const float4*)&qkv[base + (size_t)(kt * 64 + r) * 1536 + 512 + h * 64 + lc4 * 4];
        __syncthreads();

        float s[4][4] = {};
#pragma unroll 4
        for (int d0 = 0; d0 < 64; d0 += 4) {
            float4 qv[4], kv[4];
#pragma unroll
            for (int i = 0; i < 4; ++i) qv[i] = *(const float4*)&Qs[tm * 4 + i][d0];
#pragma unroll
            for (int j = 0; j < 4; ++j) kv[j] = *(const float4*)&KVs[tn + 16 * j][d0];
#pragma unroll
            for (int i = 0; i < 4; ++i)
#pragma unroll
                for (int j = 0; j < 4; ++j) {
                    s[i][j] = fmaf(qv[i].x, kv[j].x, s[i][j]);
                    s[i][j] = fmaf(qv[i].y, kv[j].y, s[i][j]);
                    s[i][j] = fmaf(qv[i].z, kv[j].z, s[i][j]);
                    s[i][j] = fmaf(qv[i].w, kv[j].w, s[i][j]);
                }
        }

#pragma unroll
        for (int i = 0; i < 4; ++i) {
            float tmax = -INFINITY;
#pragma unroll
            for (int j = 0; j < 4; ++j) { s[i][j] *= SCALE_; tmax = fmaxf(tmax, s[i][j]); }
            tmax = fmaxf(tmax, __shfl_xor(tmax, 1, 16));
            tmax = fmaxf(tmax, __shfl_xor(tmax, 2, 16));
            tmax = fmaxf(tmax, __shfl_xor(tmax, 4, 16));
            tmax = fmaxf(tmax, __shfl_xor(tmax, 8, 16));
            const float mnew = fmaxf(m[i], tmax);
            const float corr = __expf(m[i] - mnew);
            float psum = 0.f;
#pragma unroll
            for (int j = 0; j < 4; ++j) {
                s[i][j] = __expf(s[i][j] - mnew);
                psum += s[i][j];
            }
            psum += __shfl_xor(psum, 1, 16);
            psum += __shfl_xor(psum, 2, 16);
            psum += __shfl_xor(psum, 4, 16);
            psum += __shfl_xor(psum, 8, 16);
            l[i] = l[i] * corr + psum;
            m[i] = mnew;
#pragma unroll
            for (int dd = 0; dd < 4; ++dd) o[i][dd] *= corr;
        }

#pragma unroll
        for (int i = 0; i < 4; ++i)
#pragma unroll
            for (int j = 0; j < 4; ++j)
                Ps[tm * 4 + i][tn + 16 * j] = s[i][j];
        __syncthreads();

        for (int r = lr; r < 64; r += 16)
            *(float4*)&KVs[r][lc4 * 4] =
                *(const float4*)&qkv[base + (size_t)(kt * 64 + r) * 1536 + 1024 + h * 64 + lc4 * 4];
        __syncthreads();

#pragma unroll 4
        for (int j0 = 0; j0 < 64; j0 += 4) {
            float4 pv[4], vv[4];
#pragma unroll
            for (int i = 0; i < 4; ++i) pv[i] = *(const float4*)&Ps[tm * 4 + i][j0];
#pragma unroll
            for (int jj = 0; jj < 4; ++jj) vv[jj] = *(const float4*)&KVs[j0 + jj][tn * 4];
#pragma unroll
            for (int i = 0; i < 4; ++i) {
                const float pf[4] = {pv[i].x, pv[i].y, pv[i].z, pv[i].w};
                const float* vf0 = (const float*)&vv[0];
                const float* vf1 = (const float*)&vv[1];
                const float* vf2 = (const float*)&vv[2];
                const float* vf3 = (const float*)&vv[3];
#pragma unroll
                for (int dd = 0; dd < 4; ++dd) {
                    float acc = o[i][dd];
                    acc = fmaf(pf[0], vf0[dd], acc);
                    acc = fmaf(pf[1], vf1[dd], acc);
                    acc = fmaf(pf[2], vf2[dd], acc);
                    acc = fmaf(pf[3], vf3[dd], acc);
                    o[i][dd] = acc;
                }
            }
        }
        __syncthreads();
    }

#pragma unroll
    for (int i = 0; i < 4; ++i) {
        const float inv = 1.f / l[i];
        const size_t orow = (size_t)(b * NN_ + qrow0 + tm * 4 + i) * NDIM_ + h * 64 + tn * 4;
        ushort4 pk;
        pk.x = bf_bits(o[i][0] * inv);
        pk.y = bf_bits(o[i][1] * inv);
        pk.z = bf_bits(o[i][2] * inv);
        pk.w = bf_bits(o[i][3] * inv);
        *(ushort4*)&aoutb[orow] = pk;
    }
}

extern "C" void kernel_launch(void* const* d_in, const int* in_sizes, int n_in,
                              void* d_out, int out_size, void* d_ws, size_t ws_size,
                              hipStream_t stream) {
    const float* x     = (const float*)d_in[0];
    const float* w_qkv = (const float*)d_in[1];
    const float* w_out = (const float*)d_in[2];
    const float* b_out = (const float*)d_in[3];
    float* out = (float*)d_out;

    char* ws = (char*)d_ws;
    float*  qkv   = (float*)ws;                                   // 96 MiB
    ushort* xb    = (ushort*)(ws + 100663296);                    // 16 MiB (8M bf16)
    ushort* aoutb = xb;                                           // aliased (sequential use)
    ushort* wqkvT = (ushort*)(ws + 100663296 + 16777216);         // 1.5 MiB [1536,512]
    ushort* woutT = (ushort*)(ws + 100663296 + 16777216 + 1572864); // 0.5 MiB [512,512]

    const dim3 blk(256);
    // casts
    cast_bf16<<<dim3((8388608 / 4 + 255) / 256), blk, 0, stream>>>(x, xb, 8388608 / 4);
    transpose_cast<<<dim3(1536 / 32, 512 / 32), blk, 0, stream>>>(w_qkv, wqkvT, 512, 1536);
    transpose_cast<<<dim3(512 / 32, 512 / 32), blk, 0, stream>>>(w_out, woutT, 512, 512);
    // qkv = x @ w_qkv  (f32 out)
    gemm_bf16<<<dim3(1536 / 128, 16384 / 128), blk, 0, stream>>>(xb, wqkvT, nullptr, qkv,
                                                                 16384, 1536, 512);
    // attention -> bf16 aout
    attn_flash<<<dim3(16, 128), blk, 0, stream>>>(qkv, aoutb);
    // out = aout @ w_out + b_out
    gemm_bf16<<<dim3(512 / 128, 16384 / 128), blk, 0, stream>>>(aoutb, woutT, b_out, out,
                                                                16384, 512, 512);
}

// Round 4
// 244.449 us; speedup vs baseline: 8.5306x; 2.5259x over previous
//
#include <hip/hip_runtime.h>
#include <math.h>

// MHSA forward. x[16,1024,512]f32, w_qkv[512,1536], w_out[512,512], b_out[512].
// Round 4: full bf16 MFMA pipeline. GEMM1 -> bf16 qkv; V^T gather; MFMA flash attention
// (64-row Q tiles, 4 waves, XOR-swizzled K/V^T LDS, double-buffered, 16x16x32 bf16 MFMA).
// ws: qkvb bf16[16384,1536] | vT bf16[128,64,1024] | xb/aoutb bf16[16384,512] | wqkvT | woutT

#define SCALE_ 0.04419417382415922f   // 512^-0.5

typedef float f32x4 __attribute__((ext_vector_type(4)));
typedef __bf16 bf16x8 __attribute__((ext_vector_type(8)));
typedef ushort u16x8 __attribute__((ext_vector_type(8)));

static __device__ __forceinline__ ushort bf_bits(float f) {
    unsigned u = __builtin_bit_cast(unsigned, f);
    u += 0x7fffu + ((u >> 16) & 1u);          // RNE
    return (ushort)(u >> 16);
}

#define GLDS16(gsrc, ldst)                                                              \
    __builtin_amdgcn_global_load_lds((const __attribute__((address_space(1))) void*)(gsrc), \
                                     (__attribute__((address_space(3))) void*)(ldst), 16, 0, 0)

// ---------------- cast f32 -> bf16 ----------------
__global__ __launch_bounds__(256) void cast_bf16(const float* __restrict__ in,
                                                 ushort* __restrict__ out, int n4) {
    const int i = blockIdx.x * 256 + threadIdx.x;
    if (i >= n4) return;
    const float4 v = ((const float4*)in)[i];
    ushort4 o;
    o.x = bf_bits(v.x); o.y = bf_bits(v.y); o.z = bf_bits(v.z); o.w = bf_bits(v.w);
    ((ushort4*)out)[i] = o;
}

// ---------------- transpose-cast weights: in[K,N] f32 -> out[N,K] bf16 ----------------
__global__ __launch_bounds__(256) void transpose_cast(const float* __restrict__ in,
                                                      ushort* __restrict__ out,
                                                      int K, int N) {
    __shared__ float t[32][33];
    const int n0 = blockIdx.x * 32, k0 = blockIdx.y * 32;
    const int tx = threadIdx.x & 31, ty = threadIdx.x >> 5;
    for (int i = ty; i < 32; i += 8)
        t[i][tx] = in[(size_t)(k0 + i) * N + n0 + tx];
    __syncthreads();
    for (int i = ty; i < 32; i += 8)
        out[(size_t)(n0 + i) * K + k0 + tx] = bf_bits(t[tx][i]);
}

// ---------------- C = A[M,K] @ BT[N,K]^T (+bias), bf16 MFMA, f32 or bf16 out ----------------
__global__ __launch_bounds__(256) void gemm_bf16(const ushort* __restrict__ A,
                                                 const ushort* __restrict__ BT,
                                                 const float* __restrict__ bias,
                                                 float* __restrict__ C,
                                                 ushort* __restrict__ Cb,
                                                 int M, int N, int K) {
    __shared__ __align__(16) char lds[16384];   // A [128m][32k] bf16 ; B +8192 [128n][32k]
    const int tid = threadIdx.x;
    const int lane = tid & 63;
    const int w = tid >> 6;
    const int wr = w >> 1, wc = w & 1;
    const int fr = lane & 15;
    const int fg = lane >> 4;
    const int rowBase = blockIdx.y * 128;
    const int colBase = blockIdx.x * 128;

    f32x4 acc[4][4] = {};

    for (int k0 = 0; k0 < K; k0 += 32) {
#pragma unroll
        for (int r = 0; r < 2; ++r) {
            const unsigned boff = r * 4096u + w * 1024u + lane * 16u;
            const unsigned row = boff >> 6;
            const unsigned ke = (boff & 63u) >> 1;
            GLDS16(A + (size_t)(rowBase + row) * K + k0 + ke, lds + r * 4096 + w * 1024);
            GLDS16(BT + (size_t)(colBase + row) * K + k0 + ke, lds + 8192 + r * 4096 + w * 1024);
        }
        __syncthreads();

        bf16x8 a_frag[4], b_frag[4];
#pragma unroll
        for (int mi = 0; mi < 4; ++mi)
            a_frag[mi] = *(const bf16x8*)(lds + ((wr * 64 + mi * 16 + fr) * 64 + fg * 16));
#pragma unroll
        for (int ni = 0; ni < 4; ++ni)
            b_frag[ni] = *(const bf16x8*)(lds + 8192 + ((wc * 64 + ni * 16 + fr) * 64 + fg * 16));
#pragma unroll
        for (int mi = 0; mi < 4; ++mi)
#pragma unroll
            for (int ni = 0; ni < 4; ++ni)
                acc[mi][ni] = __builtin_amdgcn_mfma_f32_16x16x32_bf16(a_frag[mi], b_frag[ni],
                                                                      acc[mi][ni], 0, 0, 0);
        __syncthreads();
    }

#pragma unroll
    for (int ni = 0; ni < 4; ++ni) {
        const int col = colBase + wc * 64 + ni * 16 + fr;
        const float bv = bias ? bias[col] : 0.f;
#pragma unroll
        for (int mi = 0; mi < 4; ++mi) {
#pragma unroll
            for (int q = 0; q < 4; ++q) {
                const int row = rowBase + wr * 64 + mi * 16 + fg * 4 + q;
                const float v = acc[mi][ni][q] + bv;
                if (Cb) Cb[(size_t)row * N + col] = bf_bits(v);
                else    C[(size_t)row * N + col] = v;
            }
        }
    }
}

// ---------------- V^T gather: qkvb[16384,1536] V-cols -> vT[bh=128][dv=64][n=1024] ----------------
__global__ __launch_bounds__(256) void v_transpose(const ushort* __restrict__ qkvb,
                                                   ushort* __restrict__ vT) {
    const int t = blockIdx.x * 256 + threadIdx.x;     // 8 elems each, 8.39M total
    const int f0 = t * 8;
    const int bh = f0 >> 16;
    const int dv = (f0 >> 10) & 63;
    const int n0 = f0 & 1023;
    const int b = bh >> 3, h = bh & 7;
    u16x8 o;
#pragma unroll
    for (int e = 0; e < 8; ++e)
        o[e] = qkvb[(size_t)(b * 1024 + n0 + e) * 1536 + 1024 + h * 64 + dv];
    *(u16x8*)(vT + f0) = o;
}

// ---------------- MFMA flash attention ----------------
// WG = (qtile 64 rows, b,h), 4 waves x 16 q-rows. K/V^T tiles [64][64] bf16 in LDS,
// XOR-swizzle byte^((row&7)<<4), double-buffered. Q in regs. P restaged via per-wave LDS.
__global__ __launch_bounds__(256) void attn_mfma(const ushort* __restrict__ qkv,
                                                 const ushort* __restrict__ vT,
                                                 ushort* __restrict__ aoutb) {
    __shared__ __align__(16) char lds[40960];  // K:[2]x8KB @0 ; VT:[2]x8KB @16384 ; P: @32768 + w*2048
    const int qt = blockIdx.x;          // 16
    const int bh = blockIdx.y;          // 128
    const int b = bh >> 3, h = bh & 7;
    const int tid = threadIdx.x;
    const int lane = tid & 63;
    const int w = tid >> 6;
    const int fr = lane & 15;
    const int fg = lane >> 4;

    const size_t nbase = (size_t)b * 1024;
    const int qrow0 = qt * 64;

    // Q fragments (2 k-steps) straight from global
    bf16x8 qf[2];
    {
        const size_t qa = (nbase + qrow0 + w * 16 + fr) * 1536 + h * 64;
        qf[0] = *(const bf16x8*)(qkv + qa + fg * 8);
        qf[1] = *(const bf16x8*)(qkv + qa + 32 + fg * 8);
    }

    // stage K + V^T tile kt into buffer buf (per wave: rows w*16..+15, pre-swizzled source)
    const int srow = w * 16 + (lane >> 3);   // rows this lane covers (r=0); +8 for r=1
    const int slot = lane & 7;
    auto stage = [&](int kt, int buf) {
        char* kd = lds + buf * 8192;
        char* vd = lds + 16384 + buf * 8192;
#pragma unroll
        for (int r = 0; r < 2; ++r) {
            const int row = srow + r * 8;
            const int sw = slot ^ (row & 7);
            GLDS16(qkv + (nbase + kt * 64 + row) * 1536 + 512 + h * 64 + sw * 8,
                   kd + (w * 2 + r) * 1024);
            GLDS16(vT + ((size_t)bh * 64 + row) * 1024 + kt * 64 + sw * 8,
                   vd + (w * 2 + r) * 1024);
        }
    };

    f32x4 o[4] = {};                      // o[dvb][q]
    float mrow[4], lrow[4];
#pragma unroll
    for (int q = 0; q < 4; ++q) { mrow[q] = -INFINITY; lrow[q] = 0.f; }

    stage(0, 0);
    __syncthreads();
    int cur = 0;
    char* const pbase = lds + 32768 + w * 2048;

    for (int kt = 0; kt < 16; ++kt) {
        if (kt < 15) stage(kt + 1, cur ^ 1);
        const char* kb = lds + cur * 8192;
        const char* vb = lds + 16384 + cur * 8192;

        // ---- S = Q K^T ----
        f32x4 S[4];
#pragma unroll
        for (int jb = 0; jb < 4; ++jb) {
            f32x4 a = {};
#pragma unroll
            for (int s = 0; s < 2; ++s) {
                const int row = jb * 16 + fr;
                const int c = s * 64 + fg * 16;
                const bf16x8 kf = *(const bf16x8*)(kb + row * 128 + (c ^ ((row & 7) << 4)));
                a = __builtin_amdgcn_mfma_f32_16x16x32_bf16(qf[s], kf, a, 0, 0, 0);
            }
            S[jb] = a;
        }

        // ---- online softmax (rows fg*4+q; 16 lanes of same fg share rows) ----
        ushort pk[4][4];
#pragma unroll
        for (int q = 0; q < 4; ++q) {
            float sv[4];
            float tmax = -INFINITY;
#pragma unroll
            for (int jb = 0; jb < 4; ++jb) { sv[jb] = S[jb][q] * SCALE_; tmax = fmaxf(tmax, sv[jb]); }
            tmax = fmaxf(tmax, __shfl_xor(tmax, 1, 16));
            tmax = fmaxf(tmax, __shfl_xor(tmax, 2, 16));
            tmax = fmaxf(tmax, __shfl_xor(tmax, 4, 16));
            tmax = fmaxf(tmax, __shfl_xor(tmax, 8, 16));
            const float mnew = fmaxf(mrow[q], tmax);
            const float corr = __expf(mrow[q] - mnew);
            float psum = 0.f;
#pragma unroll
            for (int jb = 0; jb < 4; ++jb) {
                sv[jb] = __expf(sv[jb] - mnew);
                psum += sv[jb];
                pk[q][jb] = bf_bits(sv[jb]);
            }
            psum += __shfl_xor(psum, 1, 16);
            psum += __shfl_xor(psum, 2, 16);
            psum += __shfl_xor(psum, 4, 16);
            psum += __shfl_xor(psum, 8, 16);
            lrow[q] = lrow[q] * corr + psum;
            mrow[q] = mnew;
#pragma unroll
            for (int dvb = 0; dvb < 4; ++dvb) o[dvb][q] *= corr;
        }

        // ---- P -> per-wave LDS (swizzled), re-fragment for PV A-operand ----
#pragma unroll
        for (int q = 0; q < 4; ++q) {
            const int prow = fg * 4 + q;
#pragma unroll
            for (int jb = 0; jb < 4; ++jb) {
                const int c = (jb * 16 + fr) * 2;
                *(ushort*)(pbase + prow * 128 + (c ^ ((prow & 7) << 4))) = pk[q][jb];
            }
        }

        // ---- O += P V ----
#pragma unroll
        for (int s = 0; s < 2; ++s) {
            const int pc = s * 64 + fg * 16;
            const bf16x8 pf = *(const bf16x8*)(pbase + fr * 128 + (pc ^ ((fr & 7) << 4)));
#pragma unroll
            for (int dvb = 0; dvb < 4; ++dvb) {
                const int vrow = dvb * 16 + fr;
                const bf16x8 vf = *(const bf16x8*)(vb + vrow * 128 + (pc ^ ((vrow & 7) << 4)));
                o[dvb] = __builtin_amdgcn_mfma_f32_16x16x32_bf16(pf, vf, o[dvb], 0, 0, 0);
            }
        }
        __syncthreads();
        cur ^= 1;
    }

#pragma unroll
    for (int q = 0; q < 4; ++q) {
        const float inv = 1.f / lrow[q];
        const size_t n = nbase + qrow0 + w * 16 + fg * 4 + q;
#pragma unroll
        for (int dvb = 0; dvb < 4; ++dvb)
            aoutb[n * 512 + h * 64 + dvb * 16 + fr] = bf_bits(o[dvb][q] * inv);
    }
}

extern "C" void kernel_launch(void* const* d_in, const int* in_sizes, int n_in,
                              void* d_out, int out_size, void* d_ws, size_t ws_size,
                              hipStream_t stream) {
    const float* x     = (const float*)d_in[0];
    const float* w_qkv = (const float*)d_in[1];
    const float* w_out = (const float*)d_in[2];
    const float* b_out = (const float*)d_in[3];
    float* out = (float*)d_out;

    char* ws = (char*)d_ws;
    ushort* qkvb  = (ushort*)ws;                                  // 48 MiB [16384,1536]
    ushort* vT    = (ushort*)(ws + 50331648);                     // 16 MiB [128,64,1024]
    ushort* xb    = (ushort*)(ws + 50331648 + 16777216);          // 16 MiB
    ushort* aoutb = xb;                                           // aliased (sequential)
    ushort* wqkvT = (ushort*)(ws + 50331648 + 33554432);          // 1.5 MiB
    ushort* woutT = (ushort*)(ws + 50331648 + 33554432 + 1572864);// 0.5 MiB

    const dim3 blk(256);
    cast_bf16<<<dim3(8388608 / 4 / 256), blk, 0, stream>>>(x, xb, 8388608 / 4);
    transpose_cast<<<dim3(1536 / 32, 512 / 32), blk, 0, stream>>>(w_qkv, wqkvT, 512, 1536);
    transpose_cast<<<dim3(512 / 32, 512 / 32), blk, 0, stream>>>(w_out, woutT, 512, 512);
    // qkv (bf16) = x @ w_qkv
    gemm_bf16<<<dim3(12, 128), blk, 0, stream>>>(xb, wqkvT, nullptr, nullptr, qkvb,
                                                 16384, 1536, 512);
    // V^T
    v_transpose<<<dim3(8388608 / 8 / 256), blk, 0, stream>>>(qkvb, vT);
    // attention
    attn_mfma<<<dim3(16, 128), blk, 0, stream>>>(qkvb, vT, aoutb);
    // out = aout @ w_out + b_out (f32)
    gemm_bf16<<<dim3(4, 128), blk, 0, stream>>>(aoutb, woutT, b_out, out, nullptr,
                                                16384, 512, 512);
}

// Round 5
// 152.029 us; speedup vs baseline: 13.7165x; 1.6079x over previous
//
#include <hip/hip_runtime.h>
#include <math.h>

// MHSA forward. x[16,1024,512]f32, w_qkv[512,1536], w_out[512,512], b_out[512].
// Round 5: swapped-QK^T in-register softmax (lane-local rows), exp2-domain logits
// (SCALE*log2e folded into W_qkv Q-cols), defer-max, cvt_pk P-pack, V^T written by GEMM1.
// ws: qkvb bf16[16384,1536] | vT bf16[128,64,1024] | xb/aoutb bf16[16384,512] | wqkvT | woutT

#define QSCALE_ 0.06376541773f        // 512^-0.5 * log2(e)
#define RESCALE_THR_ 8.0f             // log2-domain defer-max threshold

typedef float f32x4 __attribute__((ext_vector_type(4)));
typedef __bf16 bf16x8 __attribute__((ext_vector_type(8)));

static __device__ __forceinline__ ushort bf_bits(float f) {
    unsigned u = __builtin_bit_cast(unsigned, f);
    u += 0x7fffu + ((u >> 16) & 1u);          // RNE
    return (ushort)(u >> 16);
}
static __device__ __forceinline__ unsigned cvt_pk_bf16(float lo, float hi) {
    unsigned d;
    asm("v_cvt_pk_bf16_f32 %0, %1, %2" : "=v"(d) : "v"(lo), "v"(hi));
    return d;
}

#define GLDS16(gsrc, ldst)                                                              \
    __builtin_amdgcn_global_load_lds((const __attribute__((address_space(1))) void*)(gsrc), \
                                     (__attribute__((address_space(3))) void*)(ldst), 16, 0, 0)

// ---------------- cast f32 -> bf16 ----------------
__global__ __launch_bounds__(256) void cast_bf16(const float* __restrict__ in,
                                                 ushort* __restrict__ out, int n4) {
    const int i = blockIdx.x * 256 + threadIdx.x;
    if (i >= n4) return;
    const float4 v = ((const float4*)in)[i];
    ushort4 o;
    o.x = bf_bits(v.x); o.y = bf_bits(v.y); o.z = bf_bits(v.z); o.w = bf_bits(v.w);
    ((ushort4*)out)[i] = o;
}

// ---------------- transpose-cast weights: in[K,N] f32 -> out[N,K] bf16, optional row-scale ----
__global__ __launch_bounds__(256) void transpose_cast(const float* __restrict__ in,
                                                      ushort* __restrict__ out,
                                                      int K, int N, float scale, int scaleRows) {
    __shared__ float t[32][33];
    const int n0 = blockIdx.x * 32, k0 = blockIdx.y * 32;
    const int tx = threadIdx.x & 31, ty = threadIdx.x >> 5;
    for (int i = ty; i < 32; i += 8)
        t[i][tx] = in[(size_t)(k0 + i) * N + n0 + tx];
    __syncthreads();
    for (int i = ty; i < 32; i += 8) {
        const float s = (n0 + i < scaleRows) ? scale : 1.f;
        out[(size_t)(n0 + i) * K + k0 + tx] = bf_bits(t[tx][i] * s);
    }
}

// ---------------- C = A[M,K] @ BT[N,K]^T (+bias), bf16 MFMA ----------------
// Cb path: cols >= 1024 (V region) divert to vT[bh=128][dv=64][n=1024] (when VT != null).
__global__ __launch_bounds__(256) void gemm_bf16(const ushort* __restrict__ A,
                                                 const ushort* __restrict__ BT,
                                                 const float* __restrict__ bias,
                                                 float* __restrict__ C,
                                                 ushort* __restrict__ Cb,
                                                 ushort* __restrict__ VT,
                                                 int M, int N, int K) {
    __shared__ __align__(16) char lds[16384];   // A [128m][32k] bf16 ; B +8192 [128n][32k]
    const int tid = threadIdx.x;
    const int lane = tid & 63;
    const int w = tid >> 6;
    const int wr = w >> 1, wc = w & 1;
    const int fr = lane & 15;
    const int fg = lane >> 4;
    const int rowBase = blockIdx.y * 128;
    const int colBase = blockIdx.x * 128;

    f32x4 acc[4][4] = {};

    for (int k0 = 0; k0 < K; k0 += 32) {
#pragma unroll
        for (int r = 0; r < 2; ++r) {
            const unsigned boff = r * 4096u + w * 1024u + lane * 16u;
            const unsigned row = boff >> 6;
            const unsigned ke = (boff & 63u) >> 1;
            GLDS16(A + (size_t)(rowBase + row) * K + k0 + ke, lds + r * 4096 + w * 1024);
            GLDS16(BT + (size_t)(colBase + row) * K + k0 + ke, lds + 8192 + r * 4096 + w * 1024);
        }
        __syncthreads();

        bf16x8 a_frag[4], b_frag[4];
#pragma unroll
        for (int mi = 0; mi < 4; ++mi)
            a_frag[mi] = *(const bf16x8*)(lds + ((wr * 64 + mi * 16 + fr) * 64 + fg * 16));
#pragma unroll
        for (int ni = 0; ni < 4; ++ni)
            b_frag[ni] = *(const bf16x8*)(lds + 8192 + ((wc * 64 + ni * 16 + fr) * 64 + fg * 16));
#pragma unroll
        for (int mi = 0; mi < 4; ++mi)
#pragma unroll
            for (int ni = 0; ni < 4; ++ni)
                acc[mi][ni] = __builtin_amdgcn_mfma_f32_16x16x32_bf16(a_frag[mi], b_frag[ni],
                                                                      acc[mi][ni], 0, 0, 0);
        __syncthreads();
    }

#pragma unroll
    for (int ni = 0; ni < 4; ++ni) {
        const int col = colBase + wc * 64 + ni * 16 + fr;
        const float bv = bias ? bias[col] : 0.f;
#pragma unroll
        for (int mi = 0; mi < 4; ++mi) {
            const int row0 = rowBase + wr * 64 + mi * 16 + fg * 4;
            if (Cb) {
                if (VT && col >= 1024) {
                    const int hd = col - 1024;
                    const size_t vb = ((size_t)((row0 >> 10) * 8 + (hd >> 6)) * 64 + (hd & 63)) * 1024
                                      + (row0 & 1023);
                    ushort4 pk4;
                    pk4.x = bf_bits(acc[mi][ni][0]);
                    pk4.y = bf_bits(acc[mi][ni][1]);
                    pk4.z = bf_bits(acc[mi][ni][2]);
                    pk4.w = bf_bits(acc[mi][ni][3]);
                    *(ushort4*)(VT + vb) = pk4;
                } else {
#pragma unroll
                    for (int q = 0; q < 4; ++q)
                        Cb[(size_t)(row0 + q) * N + col] = bf_bits(acc[mi][ni][q]);
                }
            } else {
#pragma unroll
                for (int q = 0; q < 4; ++q)
                    C[(size_t)(row0 + q) * N + col] = acc[mi][ni][q] + bv;
            }
        }
    }
}

// ---------------- MFMA flash attention, swapped QK^T, in-register softmax ----------------
// WG = (qtile 64 rows, b,h), 4 waves x 16 q-rows. Logits arrive in log2 domain (Q pre-scaled).
__global__ __launch_bounds__(256) void attn_mfma(const ushort* __restrict__ qkv,
                                                 const ushort* __restrict__ vT,
                                                 ushort* __restrict__ aoutb) {
    __shared__ __align__(16) char lds[40960];  // K:[2]x8KB @0 ; VT:[2]x8KB @16384 ; P: @32768 + w*2048
    const int qt = blockIdx.x;          // 16
    const int bh = blockIdx.y;          // 128
    const int b = bh >> 3, h = bh & 7;
    const int tid = threadIdx.x;
    const int lane = tid & 63;
    const int w = tid >> 6;
    const int fr = lane & 15;
    const int fg = lane >> 4;

    const size_t nbase = (size_t)b * 1024;
    const int qrow0 = qt * 64;

    // Q fragments (B-operand; lane holds Q[q=fr][d-slice]); Q pre-scaled by 512^-.5*log2e
    bf16x8 qf[2];
    {
        const size_t qa = (nbase + qrow0 + w * 16 + fr) * 1536 + h * 64;
        qf[0] = *(const bf16x8*)(qkv + qa + fg * 8);
        qf[1] = *(const bf16x8*)(qkv + qa + 32 + fg * 8);
    }

    const int srow = w * 16 + (lane >> 3);
    const int slot = lane & 7;
    auto stage = [&](int kt, int buf) {
        char* kd = lds + buf * 8192;
        char* vd = lds + 16384 + buf * 8192;
#pragma unroll
        for (int r = 0; r < 2; ++r) {
            const int row = srow + r * 8;
            const int sw = slot ^ (row & 7);
            GLDS16(qkv + (nbase + kt * 64 + row) * 1536 + 512 + h * 64 + sw * 8,
                   kd + (w * 2 + r) * 1024);
            GLDS16(vT + ((size_t)bh * 64 + row) * 1024 + kt * 64 + sw * 8,
                   vd + (w * 2 + r) * 1024);
        }
    };

    f32x4 o[4] = {};                      // o[dvb]: q = fg*4+r, dv = dvb*16+fr
    float mrow = -INFINITY, lrow = 0.f;   // softmax state for q = fr (log2 domain)

    stage(0, 0);
    __syncthreads();
    int cur = 0;
    char* const pbase = lds + 32768 + w * 2048;   // per-wave P[16 q][64 k] bf16, swizzled

    for (int kt = 0; kt < 16; ++kt) {
        if (kt < 15) stage(kt + 1, cur ^ 1);
        const char* kb = lds + cur * 8192;
        const char* vb = lds + 16384 + cur * 8192;

        // ---- S^T = K Q^T : lane (fr,fg) holds S[k=jb*16+fg*4+r][q=fr] ----
        f32x4 S[4];
#pragma unroll
        for (int jb = 0; jb < 4; ++jb) {
            f32x4 a = {};
#pragma unroll
            for (int s = 0; s < 2; ++s) {
                const int row = jb * 16 + fr;
                const int c = s * 64 + fg * 16;
                const bf16x8 kf = *(const bf16x8*)(kb + row * 128 + (c ^ ((row & 7) << 4)));
                a = __builtin_amdgcn_mfma_f32_16x16x32_bf16(kf, qf[s], a, 0, 0, 0);
            }
            S[jb] = a;
        }

        // ---- lane-local row max (16 vals) + cross-fg combine ----
        float tmax = -INFINITY;
#pragma unroll
        for (int jb = 0; jb < 4; ++jb)
#pragma unroll
            for (int r = 0; r < 4; ++r) tmax = fmaxf(tmax, S[jb][r]);
        tmax = fmaxf(tmax, __shfl_xor(tmax, 16));
        tmax = fmaxf(tmax, __shfl_xor(tmax, 32));

        // ---- defer-max: rescale only when a row grew > THR ----
        if (!__all(tmax - mrow <= RESCALE_THR_)) {
            const float mnew = fmaxf(mrow, tmax);
            const float corr = __builtin_amdgcn_exp2f(mrow - mnew);
            mrow = mnew;
            lrow *= corr;
#pragma unroll
            for (int r = 0; r < 4; ++r) {
                const float cr = __shfl(corr, fg * 4 + r);
#pragma unroll
                for (int dvb = 0; dvb < 4; ++dvb) o[dvb][r] *= cr;
            }
        }

        // ---- P = 2^(S - m), row sum, pack to bf16 ----
        float psum = 0.f;
#pragma unroll
        for (int jb = 0; jb < 4; ++jb)
#pragma unroll
            for (int r = 0; r < 4; ++r) {
                const float p = __builtin_amdgcn_exp2f(S[jb][r] - mrow);
                S[jb][r] = p;
                psum += p;
            }
        psum += __shfl_xor(psum, 16);
        psum += __shfl_xor(psum, 32);
        lrow += psum;

        // ---- P -> per-wave LDS: row fr, k seg jb*16+fg*4 (b64, swizzled) ----
#pragma unroll
        for (int jb = 0; jb < 4; ++jb) {
            unsigned pk2[2];
            pk2[0] = cvt_pk_bf16(S[jb][0], S[jb][1]);
            pk2[1] = cvt_pk_bf16(S[jb][2], S[jb][3]);
            *(ulong1*)(pbase + fr * 128 + ((jb * 32 + fg * 8) ^ ((fr & 7) << 4))) =
                *(ulong1*)pk2;
        }

        // ---- O += P V : A=P[q][k] frag, B=V[dv][k] frag ----
#pragma unroll
        for (int s = 0; s < 2; ++s) {
            const int pc = s * 64 + fg * 16;
            const bf16x8 pf = *(const bf16x8*)(pbase + fr * 128 + (pc ^ ((fr & 7) << 4)));
#pragma unroll
            for (int dvb = 0; dvb < 4; ++dvb) {
                const int vrow = dvb * 16 + fr;
                const bf16x8 vf = *(const bf16x8*)(vb + vrow * 128 + (pc ^ ((vrow & 7) << 4)));
                o[dvb] = __builtin_amdgcn_mfma_f32_16x16x32_bf16(pf, vf, o[dvb], 0, 0, 0);
            }
        }
        __syncthreads();
        cur ^= 1;
    }

    // ---- epilogue: fetch l for this lane's o-rows (q = fg*4+r) ----
#pragma unroll
    for (int r = 0; r < 4; ++r) {
        const float linv = 1.f / __shfl(lrow, fg * 4 + r);
        const size_t n = nbase + qrow0 + w * 16 + fg * 4 + r;
#pragma unroll
        for (int dvb = 0; dvb < 4; ++dvb)
            aoutb[n * 512 + h * 64 + dvb * 16 + fr] = bf_bits(o[dvb][r] * linv);
    }
}

extern "C" void kernel_launch(void* const* d_in, const int* in_sizes, int n_in,
                              void* d_out, int out_size, void* d_ws, size_t ws_size,
                              hipStream_t stream) {
    const float* x     = (const float*)d_in[0];
    const float* w_qkv = (const float*)d_in[1];
    const float* w_out = (const float*)d_in[2];
    const float* b_out = (const float*)d_in[3];
    float* out = (float*)d_out;

    char* ws = (char*)d_ws;
    ushort* qkvb  = (ushort*)ws;                                  // 48 MiB [16384,1536] (V cols unused)
    ushort* vT    = (ushort*)(ws + 50331648);                     // 16 MiB [128,64,1024]
    ushort* xb    = (ushort*)(ws + 50331648 + 16777216);          // 16 MiB
    ushort* aoutb = xb;                                           // aliased (sequential)
    ushort* wqkvT = (ushort*)(ws + 50331648 + 33554432);          // 1.5 MiB
    ushort* woutT = (ushort*)(ws + 50331648 + 33554432 + 1572864);// 0.5 MiB

    const dim3 blk(256);
    cast_bf16<<<dim3(8388608 / 4 / 256), blk, 0, stream>>>(x, xb, 8388608 / 4);
    // Q-cols (rows 0..511 of wqkvT) pre-scaled by 512^-0.5 * log2(e)
    transpose_cast<<<dim3(1536 / 32, 512 / 32), blk, 0, stream>>>(w_qkv, wqkvT, 512, 1536,
                                                                  QSCALE_, 512);
    transpose_cast<<<dim3(512 / 32, 512 / 32), blk, 0, stream>>>(w_out, woutT, 512, 512,
                                                                 1.f, 0);
    // qkv (bf16) = x @ w_qkv ; V columns divert to vT
    gemm_bf16<<<dim3(12, 128), blk, 0, stream>>>(xb, wqkvT, nullptr, nullptr, qkvb, vT,
                                                 16384, 1536, 512);
    // attention
    attn_mfma<<<dim3(16, 128), blk, 0, stream>>>(qkvb, vT, aoutb);
    // out = aout @ w_out + b_out (f32)
    gemm_bf16<<<dim3(4, 128), blk, 0, stream>>>(aoutb, woutT, b_out, out, nullptr, nullptr,
                                                16384, 512, 512);
}